// Round 2
// 277.416 us; speedup vs baseline: 1.1893x; 1.1893x over previous
//
#include <hip/hip_runtime.h>
#include <math.h>

#define BN_ 8
#define CIN 256
#define COUT 256
#define HH 64
#define WW 64
#define HW 4096
#define KK 9
#define OC 18
#define EPS 1e-5f
#define NTOT (BN_ * COUT * HW)

// ws layout (float units):
//   off_ws: [B][18][HW]                 = 589824 floats
//   wTb:    bf16 [72][4][256][8] shorts = 294912 floats (main GEMM A image)
//   wob:    bf16 [72][4][32][8] shorts  = 36864 floats  (offset-conv A image)
//   stats:  [2][COUT]                   = 512 floats
//   xt:     bf16 [B][32][HW][8] shorts  = 4194304 floats (g8-planar x: pixel stride 16B)
#define OFF_WS 0
#define WTB_WS 589824
#define WOB_WS 884736
#define ST_WS  921600
#define XT_WS  922112

typedef float f32x4 __attribute__((ext_vector_type(4)));
typedef short s16x8 __attribute__((ext_vector_type(8)));

__device__ __forceinline__ unsigned short f2bf(float f) {
  unsigned int u = __float_as_uint(f);
  unsigned int r = (u + 0x7fffu + ((u >> 16) & 1u)) >> 16;  // RNE
  return (unsigned short)r;
}
__device__ __forceinline__ float bf2f(short s) {
  return __uint_as_float(((unsigned int)(unsigned short)s) << 16);
}

// ---------------- Kernel T: transpose x -> xt[b][g8][p][8] bf16 ----------------
// g8-planar layout: pixel stride is 16B, so bilinear-gather corner loads from
// consecutive pixels land on consecutive 16B chunks (spatially coalesced).
__global__ __launch_bounds__(256) void xpose_kernel(
    const float* __restrict__ x, unsigned short* __restrict__ xt) {
  __shared__ float s[64][65];
  const int t = threadIdx.x;
  const int p0 = blockIdx.x * 64;
  const int c0 = blockIdx.y * 64;
  const int b  = blockIdx.z;
  const float* xb = x + ((size_t)b * CIN + c0) * HW + p0;
#pragma unroll
  for (int pass = 0; pass < 4; ++pass) {
    int cr = pass * 16 + (t >> 4);
    int ps = (t & 15) * 4;
    float4 v = *(const float4*)(xb + (size_t)cr * HW + ps);
    s[ps + 0][cr] = v.x; s[ps + 1][cr] = v.y; s[ps + 2][cr] = v.z; s[ps + 3][cr] = v.w;
  }
  __syncthreads();
  unsigned short* xo = xt + (size_t)b * 32 * HW * 8;
#pragma unroll
  for (int r = 0; r < 2; ++r) {
    int flat = r * 256 + t;
    int pr = flat >> 3, sub = flat & 7;
    int g8 = (c0 >> 3) + sub;
    s16x8 v;
#pragma unroll
    for (int j = 0; j < 8; ++j) v[j] = (short)f2bf(s[pr][sub * 8 + j]);
    *(s16x8*)(xo + ((size_t)g8 * HW + p0 + pr) * 8) = v;
  }
}

// ---------------- Kernel W1: pack w_off -> bf16 fragment image (M=32 pad) ----------------
__global__ __launch_bounds__(256) void wob_kernel(
    const float* __restrict__ w_off, unsigned short* __restrict__ wob) {
  const int ki = blockIdx.x;          // 0..71
  const int kk = ki >> 3;
  const int cc0 = (ki & 7) << 5;
#pragma unroll
  for (int r = 0; r < 4; ++r) {
    int e = r * 256 + threadIdx.x;    // g*256 + m*8 + j
    int g = e >> 8, m = (e >> 3) & 31, j = e & 7;
    int c = cc0 + g * 8 + j;
    unsigned short v = 0;
    if (m < OC) v = f2bf(w_off[((size_t)m * CIN + c) * 9 + kk]);
    wob[(size_t)ki * 1024 + e] = v;
  }
}

// ---------------- Kernel A: offset conv as MFMA GEMM, K-split across waves ----------------
__global__ __launch_bounds__(256) void offset_kernel(
    const float* __restrict__ x, const unsigned short* __restrict__ wob,
    const float* __restrict__ b_off, float* __restrict__ off_ws) {
  __shared__ __align__(16) char smem[32768];
  const int t = threadIdx.x;
  const int lane = t & 63;
  const int wv = t >> 6;
  const int b = blockIdx.x & 7;
  const int h = blockIdx.x >> 3;
  const float* xb = x + (size_t)b * CIN * HW;
  const int fr = lane & 15, fq = lane >> 4;
  unsigned short* sb = (unsigned short*)smem + wv * 2048;
  float* red = (float*)smem;

  f32x4 acc[2][4] = {};

  for (int s = 0; s < 18; ++s) {
    const int ki = wv * 18 + s;
    const int kk = ki >> 3, cc0 = (ki & 7) << 5;
    const int ky = kk / 3 - 1, kx = kk % 3 - 1;
    const int y = h + ky;
    const bool yok = (y >= 0) && (y < HH);
    const int xcol = lane + kx;
    const bool ok = yok && (xcol >= 0) && (xcol < WW);

    s16x8 af[2];
    const unsigned short* ap = wob + (size_t)ki * 1024;
#pragma unroll
    for (int i = 0; i < 2; ++i)
      af[i] = *(const s16x8*)&ap[(fq * 32 + i * 16 + fr) * 8];

    const float* bp = xb + (size_t)cc0 * HW + y * WW + xcol;
#pragma unroll
    for (int g = 0; g < 4; ++g) {
      s16x8 v;
#pragma unroll
      for (int j = 0; j < 8; ++j) {
        float val = ok ? bp[(size_t)(g * 8 + j) * HW] : 0.f;
        v[j] = (short)f2bf(val);
      }
      *(s16x8*)&sb[(g * 64 + lane) * 8] = v;
    }
    __builtin_amdgcn_s_waitcnt(0);

    s16x8 bf[4];
#pragma unroll
    for (int jn = 0; jn < 4; ++jn)
      bf[jn] = *(const s16x8*)&sb[(fq * 64 + jn * 16 + fr) * 8];
#pragma unroll
    for (int i = 0; i < 2; ++i)
#pragma unroll
      for (int jn = 0; jn < 4; ++jn)
        acc[i][jn] = __builtin_amdgcn_mfma_f32_16x16x32_bf16(af[i], bf[jn], acc[i][jn], 0, 0, 0);
  }

  __syncthreads();
#pragma unroll
  for (int i = 0; i < 2; ++i)
#pragma unroll
    for (int jn = 0; jn < 4; ++jn)
#pragma unroll
      for (int rg = 0; rg < 4; ++rg)
        red[wv * 2048 + (i * 16 + fq * 4 + rg) * 64 + jn * 16 + fr] = acc[i][jn][rg];
  __syncthreads();

  const int m = t >> 3;
  const int pq = (t & 7) * 8;
  float4 v0 = make_float4(0.f, 0.f, 0.f, 0.f), v1 = v0;
#pragma unroll
  for (int w = 0; w < 4; ++w) {
    float4 a = *(float4*)&red[w * 2048 + m * 64 + pq];
    float4 c = *(float4*)&red[w * 2048 + m * 64 + pq + 4];
    v0.x += a.x; v0.y += a.y; v0.z += a.z; v0.w += a.w;
    v1.x += c.x; v1.y += c.y; v1.z += c.z; v1.w += c.w;
  }
  if (m < OC) {
    float bo = b_off[m];
    v0.x += bo; v0.y += bo; v0.z += bo; v0.w += bo;
    v1.x += bo; v1.y += bo; v1.z += bo; v1.w += bo;
    float* op = off_ws + ((size_t)b * OC + m) * HW + h * WW + pq;
    *(float4*)op = v0;
    *(float4*)(op + 4) = v1;
  }
}

// ---------------- Kernel W0: pack w -> bf16 k-major image ----------------
__global__ __launch_bounds__(256) void wtrans_kernel(
    const float* __restrict__ w, unsigned short* __restrict__ wTb) {
  const int kb = blockIdx.x;          // 0..71
  const int kk = kb >> 3;
  const int c0 = (kb & 7) << 5;
  const int o = threadIdx.x;
#pragma unroll
  for (int g = 0; g < 4; ++g)
#pragma unroll
    for (int j = 0; j < 8; ++j) {
      int c = c0 + g * 8 + j;
      wTb[(((size_t)kb * 4 + g) * 256 + o) * 8 + j] =
          f2bf(w[((size_t)o * CIN + c) * 9 + kk]);
    }
}

// ---------------- Kernel B: g8-planar gather MFMA GEMM + fused stats ----------------
// grid 512: b = bx&7 (XCD), h = bx>>3 (64-px row tile). Block 256 = 4 waves.
// Gathers read xt[b][g8][p][8]: pixel stride 16B, so each corner-load
// instruction's 64 lanes are nearly-consecutive 16B chunks (~20 lines/instr
// instead of 64, every line fully used). A-fragments come straight from wTb
// (L2-resident, coalesced, disjoint per wave) into registers, prefetched one
// iteration ahead — no s_a LDS, no global_load_lds, LDS = 8KB.
// dy/dx for kk-group k+1 are prefetched right AFTER calc(k) consumes the
// previous pair (8 iters of slack; fixes the round-1 WAR overwrite bug).
__global__ __launch_bounds__(256) void gemm_kernel(
    const unsigned short* __restrict__ xt, const unsigned short* __restrict__ wTb,
    const float* __restrict__ off_ws, const float* __restrict__ bias,
    float* __restrict__ out, float* __restrict__ stats) {
  __shared__ unsigned short s_b[2][2048];   // [buf][(g(4) x px(64)) * 8]
  const int t = threadIdx.x;
  const int lane = t & 63;
  const int wv = t >> 6;
  const int b = blockIdx.x & 7;
  const int h = blockIdx.x >> 3;
  const int p0 = h * 64;
  const int col = t & 63;              // gather pixel (column in row h)
  const int oct = t >> 6;              // channel octet (8ch) within 32-chunk
  const int fr = lane & 15, fq = lane >> 4;
  const unsigned short* xtb = xt + (size_t)b * 32 * HW * 8;
  const float* offp = off_ws + (size_t)b * OC * HW + p0 + col;

  int cofs[4];     // corner byte offsets within a g8 plane: (cy*WW+cx)*16
  float qw[4];

  auto calc = [&](int kk, float dy, float dx) {
    float py = (float)(kk / 3 - 1 + h) + dy;
    float pxx = (float)(kk % 3 - 1 + col) + dx;
    float y0f = floorf(py), x0f = floorf(pxx);
    float fy = py - y0f, fx = pxx - x0f;
    int y0 = (int)y0f, x0 = (int)x0f;
    int y1 = y0 + 1, x1 = x0 + 1;
    bool vy0 = (y0 >= 0) && (y0 < HH), vy1 = (y1 >= 0) && (y1 < HH);
    bool vx0 = (x0 >= 0) && (x0 < WW), vx1 = (x1 >= 0) && (x1 < WW);
    int cy0 = min(max(y0, 0), HH - 1), cy1 = min(max(y1, 0), HH - 1);
    int cx0 = min(max(x0, 0), WW - 1), cx1 = min(max(x1, 0), WW - 1);
    cofs[0] = (cy0 * WW + cx0) * 16;  qw[0] = (vy0 && vx0) ? (1.f - fy) * (1.f - fx) : 0.f;
    cofs[1] = (cy0 * WW + cx1) * 16;  qw[1] = (vy0 && vx1) ? (1.f - fy) * fx : 0.f;
    cofs[2] = (cy1 * WW + cx0) * 16;  qw[2] = (vy1 && vx0) ? fy * (1.f - fx) : 0.f;
    cofs[3] = (cy1 * WW + cx1) * 16;  qw[3] = (vy1 && vx1) ? fy * fx : 0.f;
  };

  s16x8 g[4];
  auto gather = [&](int c0c) {
    // plane for this thread's 8 channels: g8 = c0c/8 + oct; plane = 4096*16B
    const char* bp = (const char*)xtb + (((size_t)(c0c >> 3) + oct) << 16);
#pragma unroll
    for (int k = 0; k < 4; ++k)
      __builtin_memcpy(&g[k], bp + cofs[k], 16);
  };

  auto combine_write = [&](int buf) {
    s16x8 v;
#pragma unroll
    for (int j = 0; j < 8; ++j) {
      float val = 0.f;
#pragma unroll
      for (int k = 0; k < 4; ++k)
        val = fmaf(qw[k], bf2f(g[k][j]), val);
      v[j] = (short)f2bf(val);
    }
    *(s16x8*)&s_b[buf][(oct * 64 + col) * 8] = v;
  };

  auto load_a = [&](int iter, s16x8* af) {
    const unsigned short* ap = wTb + (((size_t)iter * 4 + fq) * 256 + wv * 64 + fr) * 8;
#pragma unroll
    for (int i = 0; i < 4; ++i)
      af[i] = *(const s16x8*)(ap + (size_t)i * 16 * 8);
  };

  f32x4 acc[4][4] = {};
  s16x8 afc[4], afn[4];
  float dyp, dxp;

  // prologue: offsets for kk=0 (sync), prefetch kk=1, A for iter 0, gather chunk 0
  {
    float dy0 = offp[0];
    float dx0 = offp[HW];
    calc(0, dy0, dx0);
    dyp = offp[2 * HW];
    dxp = offp[3 * HW];
    load_a(0, afc);
    gather(0);
    combine_write(0);
  }
  __syncthreads();

#pragma unroll 2
  for (int iter = 0; iter < 72; ++iter) {
    const int cur = iter & 1;
    s16x8 bfr[4];
#pragma unroll
    for (int j = 0; j < 4; ++j)
      bfr[j] = *(const s16x8*)&s_b[cur][(fq * 64 + j * 16 + fr) * 8];

    const int nxt = iter + 1;
    if (nxt < 72) {
      load_a(nxt, afn);                       // A for next iter -> regs
      if ((nxt & 7) == 0) {
        const int kkc = nxt >> 3;
        calc(kkc, dyp, dxp);                  // consume prefetched dy/dx
        const int kkn = kkc + 1;
        if (kkn < 9) {                        // then prefetch the NEXT pair
          dyp = offp[(size_t)(2 * kkn) * HW]; // (8 iters of slack, no WAR)
          dxp = offp[(size_t)(2 * kkn + 1) * HW];
        }
      }
      gather((nxt & 7) << 5);                 // corners for next iter -> regs
    }

#pragma unroll
    for (int i = 0; i < 4; ++i)
#pragma unroll
      for (int j = 0; j < 4; ++j)
        acc[i][j] = __builtin_amdgcn_mfma_f32_16x16x32_bf16(afc[i], bfr[j], acc[i][j], 0, 0, 0);

    if (nxt < 72) combine_write(cur ^ 1);
    __syncthreads();
#pragma unroll
    for (int i = 0; i < 4; ++i) afc[i] = afn[i];
  }

  // epilogue: + bias, store, fused per-channel sum/sumsq
#pragma unroll
  for (int i = 0; i < 4; ++i) {
#pragma unroll
    for (int rg = 0; rg < 4; ++rg) {
      int o = wv * 64 + i * 16 + fq * 4 + rg;
      float bv = bias[o];
      float* op = out + ((size_t)(b * COUT + o)) * HW + p0 + fr;
      float s = 0.f, s2 = 0.f;
#pragma unroll
      for (int j = 0; j < 4; ++j) {
        float val = acc[i][j][rg] + bv;
        op[j * 16] = val;
        s += val; s2 += val * val;
      }
#pragma unroll
      for (int m = 1; m < 16; m <<= 1) {
        s += __shfl_xor(s, m);
        s2 += __shfl_xor(s2, m);
      }
      if (fr == 0) {
        atomicAdd(&stats[o], s);
        atomicAdd(&stats[COUT + o], s2);
      }
    }
  }
}

// ---------------- Kernel D: normalize + ReLU in-place ----------------
__global__ __launch_bounds__(256) void bn_kernel(
    float* __restrict__ out, const float* __restrict__ stats,
    const float* __restrict__ gamma, const float* __restrict__ beta) {
  int i4 = (blockIdx.x * 256 + threadIdx.x) * 4;
  int o = (i4 >> 12) & (COUT - 1);
  const float inv_n = 1.f / (float)(BN_ * HW);
  float mean = stats[o] * inv_n;
  float var = stats[COUT + o] * inv_n - mean * mean;
  float sc = gamma[o] * rsqrtf(var + EPS);
  float sh = beta[o] - mean * sc;
  float4 v = *(float4*)(out + i4);
  v.x = fmaxf(fmaf(v.x, sc, sh), 0.f);
  v.y = fmaxf(fmaf(v.y, sc, sh), 0.f);
  v.z = fmaxf(fmaf(v.z, sc, sh), 0.f);
  v.w = fmaxf(fmaf(v.w, sc, sh), 0.f);
  *(float4*)(out + i4) = v;
}

extern "C" void kernel_launch(void* const* d_in, const int* in_sizes, int n_in,
                              void* d_out, int out_size, void* d_ws, size_t ws_size,
                              hipStream_t stream) {
  const float* x     = (const float*)d_in[0];
  const float* w_off = (const float*)d_in[1];
  const float* b_off = (const float*)d_in[2];
  const float* w     = (const float*)d_in[3];
  const float* bias  = (const float*)d_in[4];
  const float* gamma = (const float*)d_in[5];
  const float* beta  = (const float*)d_in[6];
  float* out = (float*)d_out;
  float* ws = (float*)d_ws;
  float* off_ws = ws + OFF_WS;
  unsigned short* wTb = (unsigned short*)(ws + WTB_WS);
  unsigned short* wob = (unsigned short*)(ws + WOB_WS);
  float* stats = ws + ST_WS;
  unsigned short* xt = (unsigned short*)(ws + XT_WS);

  hipMemsetAsync(stats, 0, 2 * COUT * sizeof(float), stream);
  xpose_kernel<<<dim3(64, 4, 8), 256, 0, stream>>>(x, xt);
  wob_kernel<<<72, 256, 0, stream>>>(w_off, wob);
  wtrans_kernel<<<72, 256, 0, stream>>>(w, wTb);
  offset_kernel<<<512, 256, 0, stream>>>(x, wob, b_off, off_ws);
  gemm_kernel<<<512, 256, 0, stream>>>(xt, wTb, off_ws, bias, out, stats);
  bn_kernel<<<NTOT / 1024, 256, 0, stream>>>(out, stats, gamma, beta);
}

// Round 3
// 234.635 us; speedup vs baseline: 1.4061x; 1.1823x over previous
//
#include <hip/hip_runtime.h>
#include <math.h>

#define BN_ 8
#define CIN 256
#define COUT 256
#define HH 64
#define WW 64
#define HW 4096
#define KK 9
#define OC 18
#define EPS 1e-5f
#define NTOT (BN_ * COUT * HW)

// ws layout (float units):
//   off_ws: [B][18][HW]                 = 589824 floats
//   wTb:    bf16 [72][4][256][8] shorts = 294912 floats (main GEMM A image)
//   wob:    bf16 [72][4][32][8] shorts  = 36864 floats  (offset-conv A image)
//   stats:  [2][COUT]                   = 512 floats
//   xt:     bf16 [B][32][HW][8] shorts  = 4194304 floats (g8-planar x: pixel stride 16B)
#define OFF_WS 0
#define WTB_WS 589824
#define WOB_WS 884736
#define ST_WS  921600
#define XT_WS  922112

typedef float f32x4 __attribute__((ext_vector_type(4)));
typedef short s16x8 __attribute__((ext_vector_type(8)));

__device__ __forceinline__ unsigned short f2bf(float f) {
  unsigned int u = __float_as_uint(f);
  unsigned int r = (u + 0x7fffu + ((u >> 16) & 1u)) >> 16;  // RNE
  return (unsigned short)r;
}
__device__ __forceinline__ float bf2f(short s) {
  return __uint_as_float(((unsigned int)(unsigned short)s) << 16);
}

// ---------------- Kernel T: transpose x -> xt[b][g8][p][8] bf16 ----------------
__global__ __launch_bounds__(256) void xpose_kernel(
    const float* __restrict__ x, unsigned short* __restrict__ xt) {
  __shared__ float s[64][65];
  const int t = threadIdx.x;
  const int p0 = blockIdx.x * 64;
  const int c0 = blockIdx.y * 64;
  const int b  = blockIdx.z;
  const float* xb = x + ((size_t)b * CIN + c0) * HW + p0;
#pragma unroll
  for (int pass = 0; pass < 4; ++pass) {
    int cr = pass * 16 + (t >> 4);
    int ps = (t & 15) * 4;
    float4 v = *(const float4*)(xb + (size_t)cr * HW + ps);
    s[ps + 0][cr] = v.x; s[ps + 1][cr] = v.y; s[ps + 2][cr] = v.z; s[ps + 3][cr] = v.w;
  }
  __syncthreads();
  unsigned short* xo = xt + (size_t)b * 32 * HW * 8;
#pragma unroll
  for (int r = 0; r < 2; ++r) {
    int flat = r * 256 + t;
    int pr = flat >> 3, sub = flat & 7;
    int g8 = (c0 >> 3) + sub;
    s16x8 v;
#pragma unroll
    for (int j = 0; j < 8; ++j) v[j] = (short)f2bf(s[pr][sub * 8 + j]);
    *(s16x8*)(xo + ((size_t)g8 * HW + p0 + pr) * 8) = v;
  }
}

// ---------------- Kernel W1: pack w_off -> bf16 fragment image (M=32 pad) ----------------
__global__ __launch_bounds__(256) void wob_kernel(
    const float* __restrict__ w_off, unsigned short* __restrict__ wob) {
  const int ki = blockIdx.x;          // 0..71
  const int kk = ki >> 3;
  const int cc0 = (ki & 7) << 5;
#pragma unroll
  for (int r = 0; r < 4; ++r) {
    int e = r * 256 + threadIdx.x;    // g*256 + m*8 + j
    int g = e >> 8, m = (e >> 3) & 31, j = e & 7;
    int c = cc0 + g * 8 + j;
    unsigned short v = 0;
    if (m < OC) v = f2bf(w_off[((size_t)m * CIN + c) * 9 + kk]);
    wob[(size_t)ki * 1024 + e] = v;
  }
}

// ---------------- Kernel A: offset conv as MFMA GEMM, K-split across waves ----------------
// Now reads xt (bf16 g8-planar): 4x16B coalesced loads per s-step instead of
// 32x4B f32 loads + 32 cvts. Values bit-identical (xt is RNE bf16 of x).
__global__ __launch_bounds__(256) void offset_kernel(
    const unsigned short* __restrict__ xt, const unsigned short* __restrict__ wob,
    const float* __restrict__ b_off, float* __restrict__ off_ws) {
  __shared__ __align__(16) char smem[32768];
  const int t = threadIdx.x;
  const int lane = t & 63;
  const int wv = t >> 6;
  const int b = blockIdx.x & 7;
  const int h = blockIdx.x >> 3;
  const unsigned short* xtb = xt + (size_t)b * 32 * HW * 8;
  const int fr = lane & 15, fq = lane >> 4;
  unsigned short* sb = (unsigned short*)smem + wv * 2048;
  float* red = (float*)smem;

  f32x4 acc[2][4] = {};

  for (int s = 0; s < 18; ++s) {
    const int ki = wv * 18 + s;
    const int kk = ki >> 3, cc0 = (ki & 7) << 5;
    const int ky = kk / 3 - 1, kx = kk % 3 - 1;
    const int y = h + ky;
    const bool yok = (y >= 0) && (y < HH);
    const int xcol = lane + kx;
    const bool ok = yok && (xcol >= 0) && (xcol < WW);
    const int pix = y * WW + xcol;

    s16x8 af[2];
    const unsigned short* ap = wob + (size_t)ki * 1024;
#pragma unroll
    for (int i = 0; i < 2; ++i)
      af[i] = *(const s16x8*)&ap[(fq * 32 + i * 16 + fr) * 8];

#pragma unroll
    for (int g = 0; g < 4; ++g) {
      s16x8 v = {0, 0, 0, 0, 0, 0, 0, 0};
      if (ok)
        __builtin_memcpy(&v, (const char*)xtb + ((((size_t)(cc0 >> 3) + g) << 16)) + (size_t)pix * 16, 16);
      *(s16x8*)&sb[(g * 64 + lane) * 8] = v;
    }
    __builtin_amdgcn_s_waitcnt(0);

    s16x8 bf[4];
#pragma unroll
    for (int jn = 0; jn < 4; ++jn)
      bf[jn] = *(const s16x8*)&sb[(fq * 64 + jn * 16 + fr) * 8];
#pragma unroll
    for (int i = 0; i < 2; ++i)
#pragma unroll
      for (int jn = 0; jn < 4; ++jn)
        acc[i][jn] = __builtin_amdgcn_mfma_f32_16x16x32_bf16(af[i], bf[jn], acc[i][jn], 0, 0, 0);
  }

  __syncthreads();
#pragma unroll
  for (int i = 0; i < 2; ++i)
#pragma unroll
    for (int jn = 0; jn < 4; ++jn)
#pragma unroll
      for (int rg = 0; rg < 4; ++rg)
        red[wv * 2048 + (i * 16 + fq * 4 + rg) * 64 + jn * 16 + fr] = acc[i][jn][rg];
  __syncthreads();

  const int m = t >> 3;
  const int pq = (t & 7) * 8;
  float4 v0 = make_float4(0.f, 0.f, 0.f, 0.f), v1 = v0;
#pragma unroll
  for (int w = 0; w < 4; ++w) {
    float4 a = *(float4*)&red[w * 2048 + m * 64 + pq];
    float4 c = *(float4*)&red[w * 2048 + m * 64 + pq + 4];
    v0.x += a.x; v0.y += a.y; v0.z += a.z; v0.w += a.w;
    v1.x += c.x; v1.y += c.y; v1.z += c.z; v1.w += c.w;
  }
  if (m < OC) {
    float bo = b_off[m];
    v0.x += bo; v0.y += bo; v0.z += bo; v0.w += bo;
    v1.x += bo; v1.y += bo; v1.z += bo; v1.w += bo;
    float* op = off_ws + ((size_t)b * OC + m) * HW + h * WW + pq;
    *(float4*)op = v0;
    *(float4*)(op + 4) = v1;
  }
}

// ---------------- Kernel W0: pack w -> bf16 k-major image ----------------
__global__ __launch_bounds__(256) void wtrans_kernel(
    const float* __restrict__ w, unsigned short* __restrict__ wTb) {
  const int kb = blockIdx.x;          // 0..71
  const int kk = kb >> 3;
  const int c0 = (kb & 7) << 5;
  const int o = threadIdx.x;
#pragma unroll
  for (int g = 0; g < 4; ++g)
#pragma unroll
    for (int j = 0; j < 8; ++j) {
      int c = c0 + g * 8 + j;
      wTb[(((size_t)kb * 4 + g) * 256 + o) * 8 + j] =
          f2bf(w[((size_t)o * CIN + c) * 9 + kk]);
    }
}

// ---------------- Kernel B: g8-planar gather MFMA GEMM + fused stats ----------------
// 2-deep gather pipeline (gE/gO register corner-sets for even/odd target
// iters) + lgkm-only barrier (raw s_barrier; global loads stay in flight
// across iterations — __syncthreads would drain vmcnt(0) and serialize).
// cofs is single-buffered (gathers need the NEW group first at boundaries);
// qw is staged in qwN and committed only after the last old-group combine.
__global__ __launch_bounds__(256) void gemm_kernel(
    const unsigned short* __restrict__ xt, const unsigned short* __restrict__ wTb,
    const float* __restrict__ off_ws, const float* __restrict__ bias,
    float* __restrict__ out, float* __restrict__ stats) {
  __shared__ unsigned short s_b[2][2048];   // [buf][(oct(4) x px(64)) * 8]
  const int t = threadIdx.x;
  const int lane = t & 63;
  const int wv = t >> 6;
  const int b = blockIdx.x & 7;
  const int h = blockIdx.x >> 3;
  const int p0 = h * 64;
  const int col = t & 63;              // gather pixel (column in row h)
  const int oct = t >> 6;              // channel octet (8ch) within 32-chunk
  const int fr = lane & 15, fq = lane >> 4;
  const unsigned short* xtb = xt + (size_t)b * 32 * HW * 8;
  const float* offp = off_ws + (size_t)b * OC * HW + p0 + col;

  int cofs[4];     // corner byte offsets within a g8 plane: (cy*WW+cx)*16
  float qw[4], qwN[4];

  auto calc = [&](int kk, float dy, float dx) {
    float py = (float)(kk / 3 - 1 + h) + dy;
    float pxx = (float)(kk % 3 - 1 + col) + dx;
    float y0f = floorf(py), x0f = floorf(pxx);
    float fy = py - y0f, fx = pxx - x0f;
    int y0 = (int)y0f, x0 = (int)x0f;
    int y1 = y0 + 1, x1 = x0 + 1;
    bool vy0 = (y0 >= 0) && (y0 < HH), vy1 = (y1 >= 0) && (y1 < HH);
    bool vx0 = (x0 >= 0) && (x0 < WW), vx1 = (x1 >= 0) && (x1 < WW);
    int cy0 = min(max(y0, 0), HH - 1), cy1 = min(max(y1, 0), HH - 1);
    int cx0 = min(max(x0, 0), WW - 1), cx1 = min(max(x1, 0), WW - 1);
    cofs[0] = (cy0 * WW + cx0) * 16;  qwN[0] = (vy0 && vx0) ? (1.f - fy) * (1.f - fx) : 0.f;
    cofs[1] = (cy0 * WW + cx1) * 16;  qwN[1] = (vy0 && vx1) ? (1.f - fy) * fx : 0.f;
    cofs[2] = (cy1 * WW + cx0) * 16;  qwN[2] = (vy1 && vx0) ? fy * (1.f - fx) : 0.f;
    cofs[3] = (cy1 * WW + cx1) * 16;  qwN[3] = (vy1 && vx1) ? fy * fx : 0.f;
  };

  s16x8 gE[4], gO[4];     // corner data for even / odd target iters
  s16x8 afE[4], afO[4];   // A-fragments for even / odd iters

  auto gather = [&](int c0c, s16x8* g) {
    const char* bp = (const char*)xtb + (((size_t)(c0c >> 3) + oct) << 16);
#pragma unroll
    for (int k = 0; k < 4; ++k)
      __builtin_memcpy(&g[k], bp + cofs[k], 16);
  };

  auto combine_write = [&](int buf, const s16x8* g) {
    s16x8 v;
#pragma unroll
    for (int j = 0; j < 8; ++j) {
      float val = 0.f;
#pragma unroll
      for (int k = 0; k < 4; ++k)
        val = fmaf(qw[k], bf2f(g[k][j]), val);
      v[j] = (short)f2bf(val);
    }
    *(s16x8*)&s_b[buf][(oct * 64 + col) * 8] = v;
  };

  auto load_a = [&](int iter, s16x8* af) {
    const unsigned short* ap = wTb + (((size_t)iter * 4 + fq) * 256 + wv * 64 + fr) * 8;
#pragma unroll
    for (int i = 0; i < 4; ++i)
      af[i] = *(const s16x8*)(ap + (size_t)i * 16 * 8);
  };

  f32x4 acc[4][4] = {};
  float dyp, dxp;

  // prologue: calc group 0, prefetch group-1 dy/dx, A(0), gather t0+t1,
  // combine t0 -> s_b[0]
  {
    float dy0 = offp[0];
    float dx0 = offp[HW];
    calc(0, dy0, dx0);
#pragma unroll
    for (int k2 = 0; k2 < 4; ++k2) qw[k2] = qwN[k2];
    dyp = offp[2 * HW];
    dxp = offp[3 * HW];
    load_a(0, afE);
    gather(0, gE);          // target 0 (even)
    gather(32, gO);         // target 1 (odd), chunk (1&7)<<5
    combine_write(0, gE);
  }
  asm volatile("s_waitcnt lgkmcnt(0)" ::: "memory");
  __builtin_amdgcn_s_barrier();

  // Body for iteration I. AFR: A-frags for I; AFL: A dest for I+1;
  // GW: gather dest (target I+2, parity I&1); GR: combine src (target I+1);
  // CUR = I&1 (literal at each call site -> all LDS/reg indices static).
#define GBODY(I, AFR, AFL, GW, GR, CUR)                                        \
  {                                                                            \
    s16x8 bfr[4];                                                              \
    _Pragma("unroll")                                                          \
    for (int j = 0; j < 4; ++j)                                                \
      bfr[j] = *(const s16x8*)&s_b[CUR][(fq * 64 + j * 16 + fr) * 8];          \
    const int nx1 = (I) + 1, nx2 = (I) + 2;                                    \
    bool newq = false;                                                         \
    if (nx1 < 72) {                                                            \
      load_a(nx1, AFL);                                                        \
      if (nx2 < 72) {                                                          \
        if ((nx2 & 7) == 0) {                                                  \
          const int kkc = nx2 >> 3;                                            \
          calc(kkc, dyp, dxp);                                                 \
          newq = true;                                                         \
          const int kkn = kkc + 1;                                             \
          if (kkn < 9) {                                                       \
            dyp = offp[(size_t)(2 * kkn) * HW];                                \
            dxp = offp[(size_t)(2 * kkn + 1) * HW];                            \
          }                                                                    \
        }                                                                      \
        gather((nx2 & 7) << 5, GW);                                            \
      }                                                                        \
    }                                                                          \
    _Pragma("unroll")                                                          \
    for (int ii = 0; ii < 4; ++ii)                                             \
      _Pragma("unroll")                                                        \
      for (int jj = 0; jj < 4; ++jj)                                           \
        acc[ii][jj] = __builtin_amdgcn_mfma_f32_16x16x32_bf16(                 \
            AFR[ii], bfr[jj], acc[ii][jj], 0, 0, 0);                           \
    if (nx1 < 72) {                                                            \
      combine_write((CUR) ^ 1, GR);                                            \
      if (newq) {                                                              \
        _Pragma("unroll")                                                      \
        for (int k2 = 0; k2 < 4; ++k2) qw[k2] = qwN[k2];                       \
      }                                                                        \
    }                                                                          \
    asm volatile("s_waitcnt lgkmcnt(0)" ::: "memory");                         \
    __builtin_amdgcn_s_barrier();                                              \
  }

  for (int m = 0; m < 36; ++m) {
    const int i0 = 2 * m;
    GBODY(i0, afE, afO, gE, gO, 0)
    GBODY(i0 + 1, afO, afE, gO, gE, 1)
  }
#undef GBODY

  // epilogue: + bias, store, fused per-channel sum/sumsq
#pragma unroll
  for (int i = 0; i < 4; ++i) {
#pragma unroll
    for (int rg = 0; rg < 4; ++rg) {
      int o = wv * 64 + i * 16 + fq * 4 + rg;
      float bv = bias[o];
      float* op = out + ((size_t)(b * COUT + o)) * HW + p0 + fr;
      float s = 0.f, s2 = 0.f;
#pragma unroll
      for (int j = 0; j < 4; ++j) {
        float val = acc[i][j][rg] + bv;
        op[j * 16] = val;
        s += val; s2 += val * val;
      }
#pragma unroll
      for (int m2 = 1; m2 < 16; m2 <<= 1) {
        s += __shfl_xor(s, m2);
        s2 += __shfl_xor(s2, m2);
      }
      if (fr == 0) {
        atomicAdd(&stats[o], s);
        atomicAdd(&stats[COUT + o], s2);
      }
    }
  }
}

// ---------------- Kernel D: normalize + ReLU in-place ----------------
__global__ __launch_bounds__(256) void bn_kernel(
    float* __restrict__ out, const float* __restrict__ stats,
    const float* __restrict__ gamma, const float* __restrict__ beta) {
  int i4 = (blockIdx.x * 256 + threadIdx.x) * 4;
  int o = (i4 >> 12) & (COUT - 1);
  const float inv_n = 1.f / (float)(BN_ * HW);
  float mean = stats[o] * inv_n;
  float var = stats[COUT + o] * inv_n - mean * mean;
  float sc = gamma[o] * rsqrtf(var + EPS);
  float sh = beta[o] - mean * sc;
  float4 v = *(float4*)(out + i4);
  v.x = fmaxf(fmaf(v.x, sc, sh), 0.f);
  v.y = fmaxf(fmaf(v.y, sc, sh), 0.f);
  v.z = fmaxf(fmaf(v.z, sc, sh), 0.f);
  v.w = fmaxf(fmaf(v.w, sc, sh), 0.f);
  *(float4*)(out + i4) = v;
}

extern "C" void kernel_launch(void* const* d_in, const int* in_sizes, int n_in,
                              void* d_out, int out_size, void* d_ws, size_t ws_size,
                              hipStream_t stream) {
  const float* x     = (const float*)d_in[0];
  const float* w_off = (const float*)d_in[1];
  const float* b_off = (const float*)d_in[2];
  const float* w     = (const float*)d_in[3];
  const float* bias  = (const float*)d_in[4];
  const float* gamma = (const float*)d_in[5];
  const float* beta  = (const float*)d_in[6];
  float* out = (float*)d_out;
  float* ws = (float*)d_ws;
  float* off_ws = ws + OFF_WS;
  unsigned short* wTb = (unsigned short*)(ws + WTB_WS);
  unsigned short* wob = (unsigned short*)(ws + WOB_WS);
  float* stats = ws + ST_WS;
  unsigned short* xt = (unsigned short*)(ws + XT_WS);

  hipMemsetAsync(stats, 0, 2 * COUT * sizeof(float), stream);
  xpose_kernel<<<dim3(64, 4, 8), 256, 0, stream>>>(x, xt);
  wob_kernel<<<72, 256, 0, stream>>>(w_off, wob);
  wtrans_kernel<<<72, 256, 0, stream>>>(w, wTb);
  offset_kernel<<<512, 256, 0, stream>>>(xt, wob, b_off, off_ws);
  gemm_kernel<<<512, 256, 0, stream>>>(xt, wTb, off_ws, bias, out, stats);
  bn_kernel<<<NTOT / 1024, 256, 0, stream>>>(out, stats, gamma, beta);
}

// Round 4
// 229.785 us; speedup vs baseline: 1.4358x; 1.0211x over previous
//
#include <hip/hip_runtime.h>
#include <math.h>

#define BN_ 8
#define CIN 256
#define COUT 256
#define HH 64
#define WW 64
#define HW 4096
#define KK 9
#define OC 18
#define EPS 1e-5f
#define NTOT (BN_ * COUT * HW)

// ws layout (float units):
//   off_ws: [B][18][HW]                 = 589824 floats
//   wTb:    bf16 [72][4][256][8] shorts = 294912 floats (main GEMM A image)
//   wob:    bf16 [72][4][32][8] shorts  = 36864 floats  (offset-conv A image)
//   stats:  [2][COUT]                   = 512 floats
//   xt:     bf16 [B][32][HW][8] shorts  = 4194304 floats (g8-planar x: pixel stride 16B)
#define OFF_WS 0
#define WTB_WS 589824
#define WOB_WS 884736
#define ST_WS  921600
#define XT_WS  922112

typedef float f32x4 __attribute__((ext_vector_type(4)));
typedef short s16x8 __attribute__((ext_vector_type(8)));

__device__ __forceinline__ unsigned short f2bf(float f) {
  unsigned int u = __float_as_uint(f);
  unsigned int r = (u + 0x7fffu + ((u >> 16) & 1u)) >> 16;  // RNE
  return (unsigned short)r;
}
__device__ __forceinline__ float bf2f(short s) {
  return __uint_as_float(((unsigned int)(unsigned short)s) << 16);
}

// ---------------- Kernel T: transpose x -> xt[b][g8][p][8] bf16 ----------------
__global__ __launch_bounds__(256) void xpose_kernel(
    const float* __restrict__ x, unsigned short* __restrict__ xt) {
  __shared__ float s[64][65];
  const int t = threadIdx.x;
  const int p0 = blockIdx.x * 64;
  const int c0 = blockIdx.y * 64;
  const int b  = blockIdx.z;
  const float* xb = x + ((size_t)b * CIN + c0) * HW + p0;
#pragma unroll
  for (int pass = 0; pass < 4; ++pass) {
    int cr = pass * 16 + (t >> 4);
    int ps = (t & 15) * 4;
    float4 v = *(const float4*)(xb + (size_t)cr * HW + ps);
    s[ps + 0][cr] = v.x; s[ps + 1][cr] = v.y; s[ps + 2][cr] = v.z; s[ps + 3][cr] = v.w;
  }
  __syncthreads();
  unsigned short* xo = xt + (size_t)b * 32 * HW * 8;
#pragma unroll
  for (int r = 0; r < 2; ++r) {
    int flat = r * 256 + t;
    int pr = flat >> 3, sub = flat & 7;
    int g8 = (c0 >> 3) + sub;
    s16x8 v;
#pragma unroll
    for (int j = 0; j < 8; ++j) v[j] = (short)f2bf(s[pr][sub * 8 + j]);
    *(s16x8*)(xo + ((size_t)g8 * HW + p0 + pr) * 8) = v;
  }
}

// ---------------- Kernel W1: pack w_off -> bf16 fragment image (M=32 pad) ----------------
__global__ __launch_bounds__(256) void wob_kernel(
    const float* __restrict__ w_off, unsigned short* __restrict__ wob) {
  const int ki = blockIdx.x;          // 0..71
  const int kk = ki >> 3;
  const int cc0 = (ki & 7) << 5;
#pragma unroll
  for (int r = 0; r < 4; ++r) {
    int e = r * 256 + threadIdx.x;    // g*256 + m*8 + j
    int g = e >> 8, m = (e >> 3) & 31, j = e & 7;
    int c = cc0 + g * 8 + j;
    unsigned short v = 0;
    if (m < OC) v = f2bf(w_off[((size_t)m * CIN + c) * 9 + kk]);
    wob[(size_t)ki * 1024 + e] = v;
  }
}

// ---------------- Kernel A: offset conv as MFMA GEMM, K-split across waves ----------------
__global__ __launch_bounds__(256) void offset_kernel(
    const unsigned short* __restrict__ xt, const unsigned short* __restrict__ wob,
    const float* __restrict__ b_off, float* __restrict__ off_ws) {
  __shared__ __align__(16) char smem[32768];
  const int t = threadIdx.x;
  const int lane = t & 63;
  const int wv = t >> 6;
  const int b = blockIdx.x & 7;
  const int h = blockIdx.x >> 3;
  const unsigned short* xtb = xt + (size_t)b * 32 * HW * 8;
  const int fr = lane & 15, fq = lane >> 4;
  unsigned short* sb = (unsigned short*)smem + wv * 2048;
  float* red = (float*)smem;

  f32x4 acc[2][4] = {};

  for (int s = 0; s < 18; ++s) {
    const int ki = wv * 18 + s;
    const int kk = ki >> 3, cc0 = (ki & 7) << 5;
    const int ky = kk / 3 - 1, kx = kk % 3 - 1;
    const int y = h + ky;
    const bool yok = (y >= 0) && (y < HH);
    const int xcol = lane + kx;
    const bool ok = yok && (xcol >= 0) && (xcol < WW);
    const int pix = y * WW + xcol;

    s16x8 af[2];
    const unsigned short* ap = wob + (size_t)ki * 1024;
#pragma unroll
    for (int i = 0; i < 2; ++i)
      af[i] = *(const s16x8*)&ap[(fq * 32 + i * 16 + fr) * 8];

#pragma unroll
    for (int g = 0; g < 4; ++g) {
      s16x8 v = {0, 0, 0, 0, 0, 0, 0, 0};
      if (ok)
        __builtin_memcpy(&v, (const char*)xtb + ((((size_t)(cc0 >> 3) + g) << 16)) + (size_t)pix * 16, 16);
      *(s16x8*)&sb[(g * 64 + lane) * 8] = v;
    }
    __builtin_amdgcn_s_waitcnt(0);

    s16x8 bf[4];
#pragma unroll
    for (int jn = 0; jn < 4; ++jn)
      bf[jn] = *(const s16x8*)&sb[(fq * 64 + jn * 16 + fr) * 8];
#pragma unroll
    for (int i = 0; i < 2; ++i)
#pragma unroll
      for (int jn = 0; jn < 4; ++jn)
        acc[i][jn] = __builtin_amdgcn_mfma_f32_16x16x32_bf16(af[i], bf[jn], acc[i][jn], 0, 0, 0);
  }

  __syncthreads();
#pragma unroll
  for (int i = 0; i < 2; ++i)
#pragma unroll
    for (int jn = 0; jn < 4; ++jn)
#pragma unroll
      for (int rg = 0; rg < 4; ++rg)
        red[wv * 2048 + (i * 16 + fq * 4 + rg) * 64 + jn * 16 + fr] = acc[i][jn][rg];
  __syncthreads();

  const int m = t >> 3;
  const int pq = (t & 7) * 8;
  float4 v0 = make_float4(0.f, 0.f, 0.f, 0.f), v1 = v0;
#pragma unroll
  for (int w = 0; w < 4; ++w) {
    float4 a = *(float4*)&red[w * 2048 + m * 64 + pq];
    float4 c = *(float4*)&red[w * 2048 + m * 64 + pq + 4];
    v0.x += a.x; v0.y += a.y; v0.z += a.z; v0.w += a.w;
    v1.x += c.x; v1.y += c.y; v1.z += c.z; v1.w += c.w;
  }
  if (m < OC) {
    float bo = b_off[m];
    v0.x += bo; v0.y += bo; v0.z += bo; v0.w += bo;
    v1.x += bo; v1.y += bo; v1.z += bo; v1.w += bo;
    float* op = off_ws + ((size_t)b * OC + m) * HW + h * WW + pq;
    *(float4*)op = v0;
    *(float4*)(op + 4) = v1;
  }
}

// ---------------- Kernel W0: pack w -> bf16 k-major image ----------------
__global__ __launch_bounds__(256) void wtrans_kernel(
    const float* __restrict__ w, unsigned short* __restrict__ wTb) {
  const int kb = blockIdx.x;          // 0..71
  const int kk = kb >> 3;
  const int c0 = (kb & 7) << 5;
  const int o = threadIdx.x;
#pragma unroll
  for (int g = 0; g < 4; ++g)
#pragma unroll
    for (int j = 0; j < 8; ++j) {
      int c = c0 + g * 8 + j;
      wTb[(((size_t)kb * 4 + g) * 256 + o) * 8 + j] =
          f2bf(w[((size_t)o * CIN + c) * 9 + kk]);
    }
}

// ---------------- Kernel B: g8-planar gather MFMA GEMM + fused stats ----------------
// 512 threads = 8 waves, wave M-tile 32, K-step 64 ch per barrier (36 iters).
// Same grid (512) and total work as before, but 16 waves/CU (4/SIMD) instead
// of 8 (2/SIMD): latency stalls (ds_read->MFMA, gather->combine, barrier skew)
// now have 3 other waves to hide under. Half the barriers, half the per-thread
// combine work. A-frags single-buffered (loaded at body top, used after the
// ~250cy combine); B-frags read inline in the MFMA loop to cap VGPR pressure.
// launch_bounds(512,4): 4 waves/SIMD -> VGPR cap 128 -> 2 blocks/CU.
__global__ __launch_bounds__(512, 4) void gemm_kernel(
    const unsigned short* __restrict__ xt, const unsigned short* __restrict__ wTb,
    const float* __restrict__ off_ws, const float* __restrict__ bias,
    float* __restrict__ out, float* __restrict__ stats) {
  __shared__ unsigned short s_b[2][4096];   // [buf][oct(8)][px(64)][8]
  const int t = threadIdx.x;
  const int lane = t & 63;
  const int wv = t >> 6;               // 0..7
  const int b = blockIdx.x & 7;
  const int h = blockIdx.x >> 3;
  const int p0 = h * 64;
  const int col = t & 63;              // gather pixel (column in row h)
  const int oct = t >> 6;              // channel octet (8ch) within 64-chunk
  const int fr = lane & 15, fq = lane >> 4;
  const unsigned short* xtb = xt + (size_t)b * 32 * HW * 8;
  const float* offp = off_ws + (size_t)b * OC * HW + p0 + col;

  int cofs[4];     // corner byte offsets within a g8 plane: (cy*WW+cx)*16
  float qw[4], qwN[4];

  auto calc = [&](int kk, float dy, float dx) {
    float py = (float)(kk / 3 - 1 + h) + dy;
    float pxx = (float)(kk % 3 - 1 + col) + dx;
    float y0f = floorf(py), x0f = floorf(pxx);
    float fy = py - y0f, fx = pxx - x0f;
    int y0 = (int)y0f, x0 = (int)x0f;
    int y1 = y0 + 1, x1 = x0 + 1;
    bool vy0 = (y0 >= 0) && (y0 < HH), vy1 = (y1 >= 0) && (y1 < HH);
    bool vx0 = (x0 >= 0) && (x0 < WW), vx1 = (x1 >= 0) && (x1 < WW);
    int cy0 = min(max(y0, 0), HH - 1), cy1 = min(max(y1, 0), HH - 1);
    int cx0 = min(max(x0, 0), WW - 1), cx1 = min(max(x1, 0), WW - 1);
    cofs[0] = (cy0 * WW + cx0) * 16;  qwN[0] = (vy0 && vx0) ? (1.f - fy) * (1.f - fx) : 0.f;
    cofs[1] = (cy0 * WW + cx1) * 16;  qwN[1] = (vy0 && vx1) ? (1.f - fy) * fx : 0.f;
    cofs[2] = (cy1 * WW + cx0) * 16;  qwN[2] = (vy1 && vx0) ? fy * (1.f - fx) : 0.f;
    cofs[3] = (cy1 * WW + cx1) * 16;  qwN[3] = (vy1 && vx1) ? fy * fx : 0.f;
  };

  s16x8 gE[4], gO[4];     // corner data for even / odd target iters

  auto gather = [&](int chunk64, s16x8* g) {
    // plane for this thread's 8 channels: g8 = chunk64*8 + oct; plane = 64KB
    const char* bp = (const char*)xtb + (((size_t)(chunk64 * 8 + oct)) << 16);
#pragma unroll
    for (int k = 0; k < 4; ++k)
      __builtin_memcpy(&g[k], bp + cofs[k], 16);
  };

  auto combine_write = [&](int buf, const s16x8* g) {
    s16x8 v;
#pragma unroll
    for (int j = 0; j < 8; ++j) {
      float val = 0.f;
#pragma unroll
      for (int k = 0; k < 4; ++k)
        val = fmaf(qw[k], bf2f(g[k][j]), val);
      v[j] = (short)f2bf(val);
    }
    *(s16x8*)&s_b[buf][(oct * 64 + col) * 8] = v;
  };

  // A-frags for iter: 2 ki (=iter*2+ks) x 2 M-frags (M=32/wave)
  auto load_a = [&](int iter, s16x8 af[2][2]) {
#pragma unroll
    for (int ks = 0; ks < 2; ++ks) {
      const unsigned short* ap =
          wTb + (((size_t)(iter * 2 + ks) * 4 + fq) * 256 + wv * 32 + fr) * 8;
#pragma unroll
      for (int i = 0; i < 2; ++i)
        af[ks][i] = *(const s16x8*)(ap + (size_t)i * 16 * 8);
    }
  };

  f32x4 acc[2][4] = {};
  float dyp, dxp;

  // prologue: calc group 0, prefetch group-1 dy/dx, gather t0+t1, combine t0
  {
    float dy0 = offp[0];
    float dx0 = offp[HW];
    calc(0, dy0, dx0);
#pragma unroll
    for (int k2 = 0; k2 < 4; ++k2) qw[k2] = qwN[k2];
    dyp = offp[2 * HW];
    dxp = offp[3 * HW];
    gather(0, gE);          // target 0 (even), chunk 0
    gather(1, gO);          // target 1 (odd),  chunk 1
    combine_write(0, gE);
  }
  asm volatile("s_waitcnt lgkmcnt(0)" ::: "memory");
  __builtin_amdgcn_s_barrier();

  // Body for iteration I (36 iters, chunk64 = I&3, kk = I>>2).
  // GW: gather dest (target I+2); GR: combine src (target I+1); CUR = I&1.
#define GBODY(I, GW, GR, CUR)                                                  \
  {                                                                            \
    s16x8 af[2][2];                                                            \
    load_a(I, af);                                                             \
    const int nx1 = (I) + 1, nx2 = (I) + 2;                                    \
    bool newq = false;                                                         \
    if (nx1 < 36) {                                                            \
      if (nx2 < 36) {                                                          \
        if ((nx2 & 3) == 0) {                                                  \
          const int kkc = nx2 >> 2;                                            \
          calc(kkc, dyp, dxp);                                                 \
          newq = true;                                                         \
          const int kkn = kkc + 1;                                             \
          if (kkn < 9) {                                                       \
            dyp = offp[(size_t)(2 * kkn) * HW];                                \
            dxp = offp[(size_t)(2 * kkn + 1) * HW];                            \
          }                                                                    \
        }                                                                      \
        gather((nx2) & 3, GW);                                                 \
      }                                                                        \
      combine_write((CUR) ^ 1, GR);                                            \
      if (newq) {                                                              \
        _Pragma("unroll")                                                      \
        for (int k2 = 0; k2 < 4; ++k2) qw[k2] = qwN[k2];                       \
      }                                                                        \
    }                                                                          \
    _Pragma("unroll")                                                          \
    for (int ks = 0; ks < 2; ++ks)                                             \
      _Pragma("unroll")                                                        \
      for (int jj = 0; jj < 4; ++jj) {                                         \
        s16x8 bfr = *(const s16x8*)&s_b[CUR][((ks * 4 + fq) * 64 + jj * 16 + fr) * 8]; \
        _Pragma("unroll")                                                      \
        for (int ii = 0; ii < 2; ++ii)                                         \
          acc[ii][jj] = __builtin_amdgcn_mfma_f32_16x16x32_bf16(               \
              af[ks][ii], bfr, acc[ii][jj], 0, 0, 0);                          \
      }                                                                        \
    asm volatile("s_waitcnt lgkmcnt(0)" ::: "memory");                         \
    __builtin_amdgcn_s_barrier();                                              \
  }

  for (int m = 0; m < 18; ++m) {
    const int i0 = 2 * m;
    GBODY(i0, gE, gO, 0)
    GBODY(i0 + 1, gO, gE, 1)
  }
#undef GBODY

  // epilogue: + bias, store, fused per-channel sum/sumsq
#pragma unroll
  for (int i = 0; i < 2; ++i) {
#pragma unroll
    for (int rg = 0; rg < 4; ++rg) {
      int o = wv * 32 + i * 16 + fq * 4 + rg;
      float bv = bias[o];
      float* op = out + ((size_t)(b * COUT + o)) * HW + p0 + fr;
      float s = 0.f, s2 = 0.f;
#pragma unroll
      for (int j = 0; j < 4; ++j) {
        float val = acc[i][j][rg] + bv;
        op[j * 16] = val;
        s += val; s2 += val * val;
      }
#pragma unroll
      for (int m2 = 1; m2 < 16; m2 <<= 1) {
        s += __shfl_xor(s, m2);
        s2 += __shfl_xor(s2, m2);
      }
      if (fr == 0) {
        atomicAdd(&stats[o], s);
        atomicAdd(&stats[COUT + o], s2);
      }
    }
  }
}

// ---------------- Kernel D: normalize + ReLU in-place ----------------
__global__ __launch_bounds__(256) void bn_kernel(
    float* __restrict__ out, const float* __restrict__ stats,
    const float* __restrict__ gamma, const float* __restrict__ beta) {
  int i4 = (blockIdx.x * 256 + threadIdx.x) * 4;
  int o = (i4 >> 12) & (COUT - 1);
  const float inv_n = 1.f / (float)(BN_ * HW);
  float mean = stats[o] * inv_n;
  float var = stats[COUT + o] * inv_n - mean * mean;
  float sc = gamma[o] * rsqrtf(var + EPS);
  float sh = beta[o] - mean * sc;
  float4 v = *(float4*)(out + i4);
  v.x = fmaxf(fmaf(v.x, sc, sh), 0.f);
  v.y = fmaxf(fmaf(v.y, sc, sh), 0.f);
  v.z = fmaxf(fmaf(v.z, sc, sh), 0.f);
  v.w = fmaxf(fmaf(v.w, sc, sh), 0.f);
  *(float4*)(out + i4) = v;
}

extern "C" void kernel_launch(void* const* d_in, const int* in_sizes, int n_in,
                              void* d_out, int out_size, void* d_ws, size_t ws_size,
                              hipStream_t stream) {
  const float* x     = (const float*)d_in[0];
  const float* w_off = (const float*)d_in[1];
  const float* b_off = (const float*)d_in[2];
  const float* w     = (const float*)d_in[3];
  const float* bias  = (const float*)d_in[4];
  const float* gamma = (const float*)d_in[5];
  const float* beta  = (const float*)d_in[6];
  float* out = (float*)d_out;
  float* ws = (float*)d_ws;
  float* off_ws = ws + OFF_WS;
  unsigned short* wTb = (unsigned short*)(ws + WTB_WS);
  unsigned short* wob = (unsigned short*)(ws + WOB_WS);
  float* stats = ws + ST_WS;
  unsigned short* xt = (unsigned short*)(ws + XT_WS);

  hipMemsetAsync(stats, 0, 2 * COUT * sizeof(float), stream);
  xpose_kernel<<<dim3(64, 4, 8), 256, 0, stream>>>(x, xt);
  wob_kernel<<<72, 256, 0, stream>>>(w_off, wob);
  wtrans_kernel<<<72, 256, 0, stream>>>(w, wTb);
  offset_kernel<<<512, 256, 0, stream>>>(xt, wob, b_off, off_ws);
  gemm_kernel<<<512, 512, 0, stream>>>(xt, wTb, off_ws, bias, out, stats);
  bn_kernel<<<NTOT / 1024, 256, 0, stream>>>(out, stats, gamma, beta);
}

// Round 6
// 221.344 us; speedup vs baseline: 1.4906x; 1.0381x over previous
//
#include <hip/hip_runtime.h>
#include <math.h>

#define BN_ 8
#define CIN 256
#define COUT 256
#define HH 64
#define WW 64
#define HW 4096
#define KK 9
#define OC 18
#define EPS 1e-5f
#define NTOT (BN_ * COUT * HW)

// ws layout (float units):
//   off_ws: [B][18][HW]                 = 589824 floats
//   wTb:    bf16 [72][4][256][8] shorts = 294912 floats (main GEMM A image)
//   wob:    bf16 [72][4][32][8] shorts  = 36864 floats  (offset-conv A image)
//   stats:  [2][COUT]                   = 512 floats
//   xt:     bf16 [B][32][HW][8] shorts  = 4194304 floats (g8-planar x: pixel stride 16B)
#define OFF_WS 0
#define WTB_WS 589824
#define WOB_WS 884736
#define ST_WS  921600
#define XT_WS  922112

typedef float f32x4 __attribute__((ext_vector_type(4)));
typedef float f32x2 __attribute__((ext_vector_type(2)));
typedef short s16x8 __attribute__((ext_vector_type(8)));
typedef unsigned int u32x4 __attribute__((ext_vector_type(4)));

__device__ __forceinline__ unsigned short f2bf(float f) {
  unsigned int u = __float_as_uint(f);
  unsigned int r = (u + 0x7fffu + ((u >> 16) & 1u)) >> 16;  // RNE
  return (unsigned short)r;
}
__device__ __forceinline__ float bf2f(short s) {
  return __uint_as_float(((unsigned int)(unsigned short)s) << 16);
}

// ---------------- Kernel T: transpose x -> xt[b][g8][p][8] bf16 ----------------
__global__ __launch_bounds__(256) void xpose_kernel(
    const float* __restrict__ x, unsigned short* __restrict__ xt) {
  __shared__ float s[64][65];
  const int t = threadIdx.x;
  const int p0 = blockIdx.x * 64;
  const int c0 = blockIdx.y * 64;
  const int b  = blockIdx.z;
  const float* xb = x + ((size_t)b * CIN + c0) * HW + p0;
#pragma unroll
  for (int pass = 0; pass < 4; ++pass) {
    int cr = pass * 16 + (t >> 4);
    int ps = (t & 15) * 4;
    float4 v = *(const float4*)(xb + (size_t)cr * HW + ps);
    s[ps + 0][cr] = v.x; s[ps + 1][cr] = v.y; s[ps + 2][cr] = v.z; s[ps + 3][cr] = v.w;
  }
  __syncthreads();
  unsigned short* xo = xt + (size_t)b * 32 * HW * 8;
#pragma unroll
  for (int r = 0; r < 2; ++r) {
    int flat = r * 256 + t;
    int pr = flat >> 3, sub = flat & 7;
    int g8 = (c0 >> 3) + sub;
    s16x8 v;
#pragma unroll
    for (int j = 0; j < 8; ++j) v[j] = (short)f2bf(s[pr][sub * 8 + j]);
    *(s16x8*)(xo + ((size_t)g8 * HW + p0 + pr) * 8) = v;
  }
}

// ---------------- Kernel P: pack w_off + w, zero stats (merged prep) ----------------
__global__ __launch_bounds__(256) void prep_kernel(
    const float* __restrict__ w_off, const float* __restrict__ w,
    unsigned short* __restrict__ wob, unsigned short* __restrict__ wTb,
    float* __restrict__ stats) {
  const int kb = blockIdx.x;          // 0..71
  const int kk = kb >> 3;
  const int c0 = (kb & 7) << 5;
  const int t = threadIdx.x;
  if (kb == 71) { stats[t] = 0.f; stats[256 + t] = 0.f; }
  // w_off pack (M=32 pad)
#pragma unroll
  for (int r = 0; r < 4; ++r) {
    int e = r * 256 + t;              // g*256 + m*8 + j
    int g = e >> 8, m = (e >> 3) & 31, j = e & 7;
    int c = c0 + g * 8 + j;
    unsigned short v = 0;
    if (m < OC) v = f2bf(w_off[((size_t)m * CIN + c) * 9 + kk]);
    wob[(size_t)kb * 1024 + e] = v;
  }
  // w pack (k-major)
#pragma unroll
  for (int g = 0; g < 4; ++g)
#pragma unroll
    for (int j = 0; j < 8; ++j) {
      int c = c0 + g * 8 + j;
      wTb[(((size_t)kb * 4 + g) * 256 + t) * 8 + j] =
          f2bf(w[((size_t)t * CIN + c) * 9 + kk]);
    }
}

// ---------------- Kernel A: offset conv as MFMA GEMM, K-split across waves ----------------
__global__ __launch_bounds__(256) void offset_kernel(
    const unsigned short* __restrict__ xt, const unsigned short* __restrict__ wob,
    const float* __restrict__ b_off, float* __restrict__ off_ws) {
  __shared__ __align__(16) char smem[32768];
  const int t = threadIdx.x;
  const int lane = t & 63;
  const int wv = t >> 6;
  const int b = blockIdx.x & 7;
  const int h = blockIdx.x >> 3;
  const unsigned short* xtb = xt + (size_t)b * 32 * HW * 8;
  const int fr = lane & 15, fq = lane >> 4;
  unsigned short* sb = (unsigned short*)smem + wv * 2048;
  float* red = (float*)smem;

  f32x4 acc[2][4] = {};

  for (int s = 0; s < 18; ++s) {
    const int ki = wv * 18 + s;
    const int kk = ki >> 3, cc0 = (ki & 7) << 5;
    const int ky = kk / 3 - 1, kx = kk % 3 - 1;
    const int y = h + ky;
    const bool yok = (y >= 0) && (y < HH);
    const int xcol = lane + kx;
    const bool ok = yok && (xcol >= 0) && (xcol < WW);
    const int pix = y * WW + xcol;

    s16x8 af[2];
    const unsigned short* ap = wob + (size_t)ki * 1024;
#pragma unroll
    for (int i = 0; i < 2; ++i)
      af[i] = *(const s16x8*)&ap[(fq * 32 + i * 16 + fr) * 8];

#pragma unroll
    for (int g = 0; g < 4; ++g) {
      s16x8 v = {0, 0, 0, 0, 0, 0, 0, 0};
      if (ok)
        __builtin_memcpy(&v, (const char*)xtb + ((((size_t)(cc0 >> 3) + g) << 16)) + (size_t)pix * 16, 16);
      *(s16x8*)&sb[(g * 64 + lane) * 8] = v;
    }
    __builtin_amdgcn_s_waitcnt(0);

    s16x8 bf[4];
#pragma unroll
    for (int jn = 0; jn < 4; ++jn)
      bf[jn] = *(const s16x8*)&sb[(fq * 64 + jn * 16 + fr) * 8];
#pragma unroll
    for (int i = 0; i < 2; ++i)
#pragma unroll
      for (int jn = 0; jn < 4; ++jn)
        acc[i][jn] = __builtin_amdgcn_mfma_f32_16x16x32_bf16(af[i], bf[jn], acc[i][jn], 0, 0, 0);
  }

  __syncthreads();
#pragma unroll
  for (int i = 0; i < 2; ++i)
#pragma unroll
    for (int jn = 0; jn < 4; ++jn)
#pragma unroll
      for (int rg = 0; rg < 4; ++rg)
        red[wv * 2048 + (i * 16 + fq * 4 + rg) * 64 + jn * 16 + fr] = acc[i][jn][rg];
  __syncthreads();

  const int m = t >> 3;
  const int pq = (t & 7) * 8;
  float4 v0 = make_float4(0.f, 0.f, 0.f, 0.f), v1 = v0;
#pragma unroll
  for (int w = 0; w < 4; ++w) {
    float4 a = *(float4*)&red[w * 2048 + m * 64 + pq];
    float4 c = *(float4*)&red[w * 2048 + m * 64 + pq + 4];
    v0.x += a.x; v0.y += a.y; v0.z += a.z; v0.w += a.w;
    v1.x += c.x; v1.y += c.y; v1.z += c.z; v1.w += c.w;
  }
  if (m < OC) {
    float bo = b_off[m];
    v0.x += bo; v0.y += bo; v0.z += bo; v0.w += bo;
    v1.x += bo; v1.y += bo; v1.z += bo; v1.w += bo;
    float* op = off_ws + ((size_t)b * OC + m) * HW + h * WW + pq;
    *(float4*)op = v0;
    *(float4*)(op + 4) = v1;
  }
}

// ---------------- Kernel B: g8-planar gather MFMA GEMM + fused stats ----------------
// 512 threads = 8 waves, M=32/wave, K-step 64ch/barrier (36 iters).
// Body I: gather target I+1 (top) -> MFMA s_b[I&1] (setprio'd) -> packed-fma
// combine target I+1 into s_b[(I&1)^1] -> lgkm-only barrier. The combine is
// the phase that gates every barrier (VALUBusy 27.6% == measured combine
// cycles), so it is rewritten with v_pk_fma_f32 (float2 elementwise_fma) +
// v_cvt_pk_bf16_f32: ~100 -> ~60 VALU/thread/iter, bit-identical chain.
__global__ __launch_bounds__(512, 4) void gemm_kernel(
    const unsigned short* __restrict__ xt, const unsigned short* __restrict__ wTb,
    const float* __restrict__ off_ws, const float* __restrict__ bias,
    float* __restrict__ out, float* __restrict__ stats) {
  __shared__ unsigned short s_b[2][4096];   // [buf][oct(8)][px(64)][8]
  const int t = threadIdx.x;
  const int lane = t & 63;
  const int wv = t >> 6;               // 0..7
  const int b = blockIdx.x & 7;
  const int h = blockIdx.x >> 3;
  const int p0 = h * 64;
  const int col = t & 63;              // gather pixel (column in row h)
  const int oct = t >> 6;              // channel octet (8ch) within 64-chunk
  const int fr = lane & 15, fq = lane >> 4;
  const unsigned short* xtb = xt + (size_t)b * 32 * HW * 8;
  const float* offp = off_ws + (size_t)b * OC * HW + p0 + col;

  int cofs[4];       // corner byte offsets within a g8 plane: (cy*WW+cx)*16
  f32x2 qw2[4];      // bilinear weights, broadcast into both f32 lanes

  auto calc = [&](int kk, float dy, float dx) {
    float py = (float)(kk / 3 - 1 + h) + dy;
    float pxx = (float)(kk % 3 - 1 + col) + dx;
    float y0f = floorf(py), x0f = floorf(pxx);
    float fy = py - y0f, fx = pxx - x0f;
    int y0 = (int)y0f, x0 = (int)x0f;
    int y1 = y0 + 1, x1 = x0 + 1;
    bool vy0 = (y0 >= 0) && (y0 < HH), vy1 = (y1 >= 0) && (y1 < HH);
    bool vx0 = (x0 >= 0) && (x0 < WW), vx1 = (x1 >= 0) && (x1 < WW);
    int cy0 = min(max(y0, 0), HH - 1), cy1 = min(max(y1, 0), HH - 1);
    int cx0 = min(max(x0, 0), WW - 1), cx1 = min(max(x1, 0), WW - 1);
    float q0 = (vy0 && vx0) ? (1.f - fy) * (1.f - fx) : 0.f;
    float q1 = (vy0 && vx1) ? (1.f - fy) * fx : 0.f;
    float q2 = (vy1 && vx0) ? fy * (1.f - fx) : 0.f;
    float q3 = (vy1 && vx1) ? fy * fx : 0.f;
    cofs[0] = (cy0 * WW + cx0) * 16;  qw2[0][0] = q0; qw2[0][1] = q0;
    cofs[1] = (cy0 * WW + cx1) * 16;  qw2[1][0] = q1; qw2[1][1] = q1;
    cofs[2] = (cy1 * WW + cx0) * 16;  qw2[2][0] = q2; qw2[2][1] = q2;
    cofs[3] = (cy1 * WW + cx1) * 16;  qw2[3][0] = q3; qw2[3][1] = q3;
  };

  s16x8 g[4];        // corner data for the in-flight target iter

  auto gather = [&](int chunk64) {
    // plane for this thread's 8 channels: g8 = chunk64*8 + oct; plane = 64KB
    const char* bp = (const char*)xtb + (((size_t)(chunk64 * 8 + oct)) << 16);
#pragma unroll
    for (int k = 0; k < 4; ++k)
      __builtin_memcpy(&g[k], bp + cofs[k], 16);
  };

  // packed bilinear combine: per bf16-pair, unpack (2 ops), 4x pk_fma, 1x
  // cvt_pk RNE. Chain order per element identical to scalar fmaf version.
  auto combine_write = [&](int buf) {
    u32x4 vout;
#pragma unroll
    for (int jp = 0; jp < 4; ++jp) {
      f32x2 a = {0.f, 0.f};
#pragma unroll
      for (int k = 0; k < 4; ++k) {
        unsigned int pr = ((const unsigned int*)&g[k])[jp];
        f32x2 xv;
        xv[0] = __uint_as_float(pr << 16);
        xv[1] = __uint_as_float(pr & 0xffff0000u);
        a = __builtin_elementwise_fma(qw2[k], xv, a);
      }
      unsigned int packed;
      asm("v_cvt_pk_bf16_f32 %0, %1, %2" : "=v"(packed) : "v"(a[0]), "v"(a[1]));
      vout[jp] = packed;
    }
    *(u32x4*)&s_b[buf][(oct * 64 + col) * 8] = vout;
  };

  // A-frags for iter: 2 ki (=iter*2+ks) x 2 M-frags (M=32/wave)
  auto load_a = [&](int iter, s16x8 af[2][2]) {
#pragma unroll
    for (int ks = 0; ks < 2; ++ks) {
      const unsigned short* ap =
          wTb + (((size_t)(iter * 2 + ks) * 4 + fq) * 256 + wv * 32 + fr) * 8;
#pragma unroll
      for (int i = 0; i < 2; ++i)
        af[ks][i] = *(const s16x8*)(ap + (size_t)i * 16 * 8);
    }
  };

  f32x4 acc[2][4] = {};
  s16x8 afE[2][2], afO[2][2];
  float dyp, dxp;

  // prologue: calc group 0, prefetch group-1 dy/dx, gather+combine t0, A(0)
  {
    float dy0 = offp[0];
    float dx0 = offp[HW];
    calc(0, dy0, dx0);
    dyp = offp[2 * HW];
    dxp = offp[3 * HW];
    gather(0);
    load_a(0, afE);
    combine_write(0);
  }
  asm volatile("s_waitcnt lgkmcnt(0)" ::: "memory");
  __builtin_amdgcn_s_barrier();

  // Body I (36 iters, chunk64 = I&3, kk = I>>2). AFC: A for I; AFN: A dest
  // for I+1; CUR = I&1 (literal -> static LDS indices).
#define GBODY(I, AFC, AFN, CUR)                                                \
  {                                                                            \
    const int nx1 = (I) + 1;                                                   \
    if (nx1 < 36) {                                                            \
      if ((nx1 & 3) == 0) {                                                    \
        const int kkc = nx1 >> 2;                                              \
        calc(kkc, dyp, dxp);                                                   \
        const int kkn = kkc + 1;                                               \
        if (kkn < 9) {                                                         \
          dyp = offp[(size_t)(2 * kkn) * HW];                                  \
          dxp = offp[(size_t)(2 * kkn + 1) * HW];                              \
        }                                                                      \
      }                                                                        \
      gather(nx1 & 3);                                                         \
      load_a(nx1, AFN);                                                        \
    }                                                                          \
    __builtin_amdgcn_s_setprio(1);                                             \
    _Pragma("unroll")                                                          \
    for (int ks = 0; ks < 2; ++ks)                                             \
      _Pragma("unroll")                                                        \
      for (int jj = 0; jj < 4; ++jj) {                                         \
        s16x8 bfr = *(const s16x8*)&s_b[CUR][((ks * 4 + fq) * 64 + jj * 16 + fr) * 8]; \
        _Pragma("unroll")                                                      \
        for (int ii = 0; ii < 2; ++ii)                                         \
          acc[ii][jj] = __builtin_amdgcn_mfma_f32_16x16x32_bf16(               \
              AFC[ks][ii], bfr, acc[ii][jj], 0, 0, 0);                         \
      }                                                                        \
    __builtin_amdgcn_s_setprio(0);                                             \
    if (nx1 < 36) {                                                            \
      combine_write((CUR) ^ 1);                                                \
      asm volatile("s_waitcnt lgkmcnt(0)" ::: "memory");                       \
      __builtin_amdgcn_s_barrier();                                            \
    }                                                                          \
  }

  for (int m = 0; m < 18; ++m) {
    const int i0 = 2 * m;
    GBODY(i0, afE, afO, 0)
    GBODY(i0 + 1, afO, afE, 1)
  }
#undef GBODY

  // epilogue: + bias, store, fused per-channel sum/sumsq
#pragma unroll
  for (int i = 0; i < 2; ++i) {
#pragma unroll
    for (int rg = 0; rg < 4; ++rg) {
      int o = wv * 32 + i * 16 + fq * 4 + rg;
      float bv = bias[o];
      float* op = out + ((size_t)(b * COUT + o)) * HW + p0 + fr;
      float s = 0.f, s2 = 0.f;
#pragma unroll
      for (int j = 0; j < 4; ++j) {
        float val = acc[i][j][rg] + bv;
        op[j * 16] = val;
        s += val; s2 += val * val;
      }
#pragma unroll
      for (int m2 = 1; m2 < 16; m2 <<= 1) {
        s += __shfl_xor(s, m2);
        s2 += __shfl_xor(s2, m2);
      }
      if (fr == 0) {
        atomicAdd(&stats[o], s);
        atomicAdd(&stats[COUT + o], s2);
      }
    }
  }
}

// ---------------- Kernel D: normalize + ReLU in-place ----------------
__global__ __launch_bounds__(256) void bn_kernel(
    float* __restrict__ out, const float* __restrict__ stats,
    const float* __restrict__ gamma, const float* __restrict__ beta) {
  int i4 = (blockIdx.x * 256 + threadIdx.x) * 4;
  int o = (i4 >> 12) & (COUT - 1);
  const float inv_n = 1.f / (float)(BN_ * HW);
  float mean = stats[o] * inv_n;
  float var = stats[COUT + o] * inv_n - mean * mean;
  float sc = gamma[o] * rsqrtf(var + EPS);
  float sh = beta[o] - mean * sc;
  float4 v = *(float4*)(out + i4);
  v.x = fmaxf(fmaf(v.x, sc, sh), 0.f);
  v.y = fmaxf(fmaf(v.y, sc, sh), 0.f);
  v.z = fmaxf(fmaf(v.z, sc, sh), 0.f);
  v.w = fmaxf(fmaf(v.w, sc, sh), 0.f);
  *(float4*)(out + i4) = v;
}

extern "C" void kernel_launch(void* const* d_in, const int* in_sizes, int n_in,
                              void* d_out, int out_size, void* d_ws, size_t ws_size,
                              hipStream_t stream) {
  const float* x     = (const float*)d_in[0];
  const float* w_off = (const float*)d_in[1];
  const float* b_off = (const float*)d_in[2];
  const float* w     = (const float*)d_in[3];
  const float* bias  = (const float*)d_in[4];
  const float* gamma = (const float*)d_in[5];
  const float* beta  = (const float*)d_in[6];
  float* out = (float*)d_out;
  float* ws = (float*)d_ws;
  float* off_ws = ws + OFF_WS;
  unsigned short* wTb = (unsigned short*)(ws + WTB_WS);
  unsigned short* wob = (unsigned short*)(ws + WOB_WS);
  float* stats = ws + ST_WS;
  unsigned short* xt = (unsigned short*)(ws + XT_WS);

  xpose_kernel<<<dim3(64, 4, 8), 256, 0, stream>>>(x, xt);
  prep_kernel<<<72, 256, 0, stream>>>(w_off, w, wob, wTb, stats);
  offset_kernel<<<512, 256, 0, stream>>>(xt, wob, b_off, off_ws);
  gemm_kernel<<<512, 512, 0, stream>>>(xt, wTb, off_ws, bias, out, stats);
  bn_kernel<<<NTOT / 1024, 256, 0, stream>>>(out, stats, gamma, beta);
}